// Round 4
// baseline (854.817 us; speedup 1.0000x reference)
//
#include <hip/hip_runtime.h>

// GRU last-hidden: B=1024, C=64, T=1024, H=32, G=96, fp32.
// x:(B,64,1024) W_ih:(96,64) W_hh:(96,32) b_ih,b_hh:(96) out:(B,32)
//
// 256 blocks x 512 threads; block = 4 batches, 8 waves:
//   waves 0-3 = producers: gx tile (32t x 96g) via MFMA bf16 hi/lo 3-product
//               split; W_ih B-frags held in REGISTERS (96 VGPR), batch = wid
//   waves 4-7 = consumers: recurrence; h broadcast via v_readlane->SGPR->fma
//
// __launch_bounds__(512,2): 8 waves/CU = 2/EU -> VGPR cap 256 (R3's default
// cap of 128 caused scratch spills: WRITE_SIZE 39MB, +80MB FETCH).
//
// LDS (159744 B):
//   wfH/wfL: W_ih MFMA B-frags bf16 hi/lo [2kt][6nt][64lane][8]  24576 B (init only)
//   xs:      x tiles [4 wave][64 c][32 t], t XOR-swizzled by (c>>3)&3  32768 B
//   gxs:     [2 buf][4 batch][32 t][100 g] fp32                      102400 B

typedef short bf16x8 __attribute__((ext_vector_type(8)));
typedef float f32x4  __attribute__((ext_vector_type(4)));

#define TT 32
#define GXS 100
#define LDS_BYTES 159744

#define GLL16(gp, lp)                                                        \
  __builtin_amdgcn_global_load_lds(                                          \
      (const __attribute__((address_space(1))) void*)(gp),                   \
      (__attribute__((address_space(3))) void*)(lp), 16, 0, 0)

static __device__ __forceinline__ short f2bf(float f) {   // RNE float->bf16
    unsigned u = __float_as_uint(f);
    u += 0x7fffu + ((u >> 16) & 1u);
    return (short)(u >> 16);
}
static __device__ __forceinline__ float bf2f(short s) {
    return __uint_as_float(((unsigned)(unsigned short)s) << 16);
}

__global__ __launch_bounds__(512, 2) void gru_fused4(
    const float* __restrict__ x,
    const float* __restrict__ W_ih,
    const float* __restrict__ W_hh,
    const float* __restrict__ b_ih,
    const float* __restrict__ b_hh,
    float* __restrict__ out)
{
    extern __shared__ char smem[];
    short* wfH = (short*)smem;                    // 768 frags * 8 shorts
    short* wfL = (short*)(smem + 12288);
    float* xs  = (float*)(smem + 24576);          // 4 * 2048 floats
    float* gxs = (float*)(smem + 57344);          // 2*4*32*100 floats

    const int tid  = threadIdx.x;
    const int wid  = tid >> 6;
    const int lane = tid & 63;
    const int bid  = blockIdx.x;

    // ---- one-time: W_ih -> bf16 hi/lo MFMA B-fragments in LDS ----
    for (int f = tid; f < 768; f += 512) {
        int slot = f & 63, ktnt = f >> 6;
        int kt = ktnt / 6, nt = ktnt - kt * 6;
        int g  = nt * 16 + (slot & 15);
        int c0 = kt * 32 + (slot >> 4) * 8;
        const float* wr = W_ih + g * 64 + c0;
        bf16x8 hi, lo;
        #pragma unroll
        for (int j = 0; j < 8; ++j) {
            float v  = wr[j];
            short hb = f2bf(v);
            hi[j] = hb;
            lo[j] = f2bf(v - bf2f(hb));
        }
        *(bf16x8*)(wfH + f * 8) = hi;
        *(bf16x8*)(wfL + f * 8) = lo;
    }

    // ================= producer state =================
    const float* xb = nullptr;
    float bias6[6];
    if (wid < 4) {
        xb = x + (size_t)(bid * 4 + wid) * 64 * 1024;
        #pragma unroll
        for (int nt = 0; nt < 6; ++nt) bias6[nt] = b_ih[nt * 16 + (lane & 15)];
    }

    // ================= consumer state =================
    float whr[32], whz[32], whn[32];
    float bhr = 0.f, bhz = 0.f, bhn = 0.f, hcur = 0.f;
    const int h = lane & 31;
    if (wid >= 4) {
        #pragma unroll
        for (int k = 0; k < 32; ++k) {
            whr[k] = W_hh[(h)      * 32 + k];
            whz[k] = W_hh[(32 + h) * 32 + k];
            whn[k] = W_hh[(64 + h) * 32 + k];
        }
        bhr = b_hh[h]; bhz = b_hh[32 + h]; bhn = b_hh[64 + h];
    }

    // async x-tile: lands as xs[c][t ^ (((c>>3)&3)<<2)] (XOR applied to the
    // GLOBAL source t-offset; LDS dest stays linear) -> conflict-free A-reads
    auto load_xtile = [&](int tile) {
        const int tbase = tile * TT;
        const int c_lo  = lane >> 3;
        #pragma unroll
        for (int i = 0; i < 8; ++i) {
            const int toff = ((lane & 7) ^ (i & 3)) << 2;
            const float* gp = xb + (i * 8 + c_lo) * 1024 + tbase + toff;
            float* lp = xs + wid * 2048 + i * 256;   // wave-uniform base
            GLL16(gp, lp);
        }
    };

    // W_ih B-frags in registers (producers): 24 frags * 4 VGPR = 96 VGPR
    bf16x8 BH[12], BL[12];

    // producer: gx tile via MFMA from register B-frags
    auto stage1 = [&](int buf, int prefetch_tile) {
        // A-frags: x^T (m=t, k=c), lane holds m=lane&15, k=(lane>>4)*8+j
        bf16x8 ah[2][2], al[2][2];
        #pragma unroll
        for (int mt = 0; mt < 2; ++mt) {
            const int tS = (mt * 16 + (lane & 15)) ^ ((lane >> 4) << 2);
            #pragma unroll
            for (int kt = 0; kt < 2; ++kt) {
                const int cb = kt * 32 + (lane >> 4) * 8;
                float xf[8];
                #pragma unroll
                for (int j = 0; j < 8; ++j)
                    xf[j] = xs[wid * 2048 + (cb + j) * 32 + tS];
                #pragma unroll
                for (int j = 0; j < 8; ++j) {
                    short hb = f2bf(xf[j]);
                    ah[mt][kt][j] = hb;
                    al[mt][kt][j] = f2bf(xf[j] - bf2f(hb));
                }
            }
        }
        // xs reads drained -> safe to overwrite own xs region
        asm volatile("s_waitcnt lgkmcnt(0)" ::: "memory");
        if (prefetch_tile >= 0) load_xtile(prefetch_tile);

        float* gb = gxs + buf * 12800 + wid * 3200;
        #pragma unroll
        for (int nt = 0; nt < 6; ++nt) {
            const float bias = bias6[nt];
            #pragma unroll
            for (int mt = 0; mt < 2; ++mt) {
                f32x4 acc = {bias, bias, bias, bias};
                acc = __builtin_amdgcn_mfma_f32_16x16x32_bf16(ah[mt][0], BH[nt],     acc, 0, 0, 0);
                acc = __builtin_amdgcn_mfma_f32_16x16x32_bf16(ah[mt][1], BH[6 + nt], acc, 0, 0, 0);
                acc = __builtin_amdgcn_mfma_f32_16x16x32_bf16(ah[mt][0], BL[nt],     acc, 0, 0, 0);
                acc = __builtin_amdgcn_mfma_f32_16x16x32_bf16(ah[mt][1], BL[6 + nt], acc, 0, 0, 0);
                acc = __builtin_amdgcn_mfma_f32_16x16x32_bf16(al[mt][0], BH[nt],     acc, 0, 0, 0);
                acc = __builtin_amdgcn_mfma_f32_16x16x32_bf16(al[mt][1], BH[6 + nt], acc, 0, 0, 0);
                // C layout: col = lane&15 (g), row = (lane>>4)*4 + reg (t)
                const int row0 = mt * 16 + ((lane >> 4) << 2);
                const int col  = nt * 16 + (lane & 15);
                #pragma unroll
                for (int j = 0; j < 4; ++j)
                    gb[(row0 + j) * GXS + col] = acc[j];
            }
        }
    };

    // consumer: 32 steps; matvec via readlane(SGPR) broadcast, zero DS ops
    auto stage2 = [&](int buf) {
        const float* gb = gxs + buf * 12800 + (wid - 4) * 3200;
        #pragma unroll 4
        for (int s = 0; s < TT; ++s) {
            const float* row = gb + s * GXS;
            float xr = row[h], xz = row[32 + h], xn = row[64 + h];
            float ar0 = 0.f, ar1 = 0.f, az0 = 0.f, az1 = 0.f, an0 = 0.f, an1 = 0.f;
            const int hb = __float_as_int(hcur);
            #pragma unroll
            for (int j = 0; j < 32; j += 2) {
                float h0 = __int_as_float(__builtin_amdgcn_readlane(hb, j));
                float h1 = __int_as_float(__builtin_amdgcn_readlane(hb, j + 1));
                ar0 = fmaf(whr[j], h0, ar0);  ar1 = fmaf(whr[j + 1], h1, ar1);
                az0 = fmaf(whz[j], h0, az0);  az1 = fmaf(whz[j + 1], h1, az1);
                an0 = fmaf(whn[j], h0, an0);  an1 = fmaf(whn[j + 1], h1, an1);
            }
            float r  = 1.f / (1.f + __expf(-(xr + ar0 + ar1 + bhr)));
            float z  = 1.f / (1.f + __expf(-(xz + az0 + az1 + bhz)));
            float nx = xn + r * (an0 + an1 + bhn);
            float n  = 1.f - 2.f / (__expf(2.f * nx) + 1.f);   // tanh
            hcur = n + z * (hcur - n);
        }
    };

    // ================= pipeline =================
    if (wid < 4) load_xtile(0);
    __syncthreads();                    // wfrag ready; xs = tile 0 (vmcnt drained)

    if (wid < 4) {
        #pragma unroll
        for (int f = 0; f < 12; ++f) {
            BH[f] = *(const bf16x8*)(wfH + (f * 64 + lane) * 8);
            BL[f] = *(const bf16x8*)(wfL + (f * 64 + lane) * 8);
        }
        stage1(0, 1);                   // gxs[0] = tile 0; prefetch tile 1
    }
    __syncthreads();                    // gxs[0] visible; xs = tile 1

    for (int k = 0; k < 32; ++k) {
        if (wid >= 4) {
            stage2(k & 1);
        } else if (k < 31) {
            stage1((k + 1) & 1, (k < 30) ? (k + 2) : -1);
        }
        __syncthreads();
    }

    if (wid >= 4 && lane < 32)
        out[(bid * 4 + (wid - 4)) * 32 + lane] = hcur;
}

extern "C" void kernel_launch(void* const* d_in, const int* in_sizes, int n_in,
                              void* d_out, int out_size, void* d_ws, size_t ws_size,
                              hipStream_t stream) {
    const float* x    = (const float*)d_in[0];
    const float* W_ih = (const float*)d_in[1];
    const float* W_hh = (const float*)d_in[2];
    const float* b_ih = (const float*)d_in[3];
    const float* b_hh = (const float*)d_in[4];
    float* out = (float*)d_out;

    hipFuncSetAttribute((const void*)gru_fused4,
                        hipFuncAttributeMaxDynamicSharedMemorySize, LDS_BYTES);
    gru_fused4<<<256, 512, LDS_BYTES, stream>>>(x, W_ih, W_hh, b_ih, b_hh, out);
}

// Round 5
// 335.473 us; speedup vs baseline: 2.5481x; 2.5481x over previous
//
#include <hip/hip_runtime.h>

// GRU last-hidden: B=1024, C=64, T=1024, H=32, G=96, fp32.
// x:(B,64,1024) W_ih:(96,64) W_hh:(96,32) b_ih,b_hh:(96) out:(B,32)
//
// 256 blocks x 512 threads; block = 4 batches, 8 waves:
//   waves 0-3 = producers: gx tile (32t x 96g) via MFMA bf16 hi/lo 3-product
//               split; B-frags read from LDS (R3 structure; register-resident
//               frags in R4 caused massive spills at the 128-VGPR cap)
//   waves 4-7 = consumers: recurrence, k-split-2 across wave halves:
//               lane = kh*32 + h owns output h with k in [kh*16, kh*16+16).
//               48 weight VGPRs (vs 96 in R3 -> was spilling), h broadcast via
//               32-float LDS buffer read as uniform-address f32x2 pairs,
//               cross-half combine via __shfl_xor(32). b_hh r/z folded into
//               producer bias (n-gate bias must stay inside r*(.)).
//
// LDS (160256 B):
//   wfH/wfL: W_ih MFMA B-frags bf16 hi/lo [2kt][6nt][64lane][8]  24576 B
//   xs:      x tiles [4 wave][64 c][32 t], t XOR-swizzled by (c>>3)&3  32768 B
//   gxs:     [2 buf][4 batch][32 t][100 g] fp32                      102400 B
//   hlds:    [4 batch][32] fp32 current h                               512 B

typedef short bf16x8 __attribute__((ext_vector_type(8)));
typedef float f32x4  __attribute__((ext_vector_type(4)));
typedef float f32x2  __attribute__((ext_vector_type(2)));

#define TT 32
#define GXS 100
#define LDS_BYTES 160256

#define GLL16(gp, lp)                                                        \
  __builtin_amdgcn_global_load_lds(                                          \
      (const __attribute__((address_space(1))) void*)(gp),                   \
      (__attribute__((address_space(3))) void*)(lp), 16, 0, 0)

static __device__ __forceinline__ short f2bf(float f) {   // RNE float->bf16
    unsigned u = __float_as_uint(f);
    u += 0x7fffu + ((u >> 16) & 1u);
    return (short)(u >> 16);
}
static __device__ __forceinline__ float bf2f(short s) {
    return __uint_as_float(((unsigned)(unsigned short)s) << 16);
}

__global__ __launch_bounds__(512) void gru_fused5(
    const float* __restrict__ x,
    const float* __restrict__ W_ih,
    const float* __restrict__ W_hh,
    const float* __restrict__ b_ih,
    const float* __restrict__ b_hh,
    float* __restrict__ out)
{
    extern __shared__ char smem[];
    short* wfH  = (short*)smem;                    // 768 frags * 8 shorts
    short* wfL  = (short*)(smem + 12288);
    float* xs   = (float*)(smem + 24576);          // 4 * 2048 floats
    float* gxs  = (float*)(smem + 57344);          // 2*4*32*100 floats
    float* hlds = (float*)(smem + 159744);         // 4*32 floats

    const int tid  = threadIdx.x;
    const int wid  = tid >> 6;
    const int lane = tid & 63;
    const int bid  = blockIdx.x;

    // ---- one-time: W_ih -> bf16 hi/lo MFMA B-fragments in LDS ----
    for (int f = tid; f < 768; f += 512) {
        int slot = f & 63, ktnt = f >> 6;
        int kt = ktnt / 6, nt = ktnt - kt * 6;
        int g  = nt * 16 + (slot & 15);
        int c0 = kt * 32 + (slot >> 4) * 8;
        const float* wr = W_ih + g * 64 + c0;
        bf16x8 hi, lo;
        #pragma unroll
        for (int j = 0; j < 8; ++j) {
            float v  = wr[j];
            short hb = f2bf(v);
            hi[j] = hb;
            lo[j] = f2bf(v - bf2f(hb));
        }
        *(bf16x8*)(wfH + f * 8) = hi;
        *(bf16x8*)(wfL + f * 8) = lo;
    }

    // ================= producer state =================
    const float* xb = nullptr;
    float bias6[6];
    if (wid < 4) {
        xb = x + (size_t)(bid * 4 + wid) * 64 * 1024;
        #pragma unroll
        for (int nt = 0; nt < 6; ++nt) {
            const int g = nt * 16 + (lane & 15);
            bias6[nt] = b_ih[g] + (nt < 4 ? b_hh[g] : 0.f);  // fold b_hh r/z
        }
    }

    // ================= consumer state (k-split-2) =================
    const int h = lane & 31, kh = lane >> 5, k0 = kh * 16;
    f32x2 wr2[8], wz2[8], wn2[8];
    float bhn = 0.f, hcur = 0.f;
    if (wid >= 4) {
        #pragma unroll
        for (int j = 0; j < 8; ++j) {
            wr2[j] = *(const f32x2*)(W_hh + (h)      * 32 + k0 + 2 * j);
            wz2[j] = *(const f32x2*)(W_hh + (32 + h) * 32 + k0 + 2 * j);
            wn2[j] = *(const f32x2*)(W_hh + (64 + h) * 32 + k0 + 2 * j);
        }
        bhn = b_hh[64 + h];
    }

    // async x-tile: lands as xs[c][t ^ (((c>>3)&3)<<2)] (XOR applied to the
    // GLOBAL source t-offset; LDS dest stays linear) -> conflict-free A-reads
    auto load_xtile = [&](int tile) {
        const int tbase = tile * TT;
        const int c_lo  = lane >> 3;
        #pragma unroll
        for (int i = 0; i < 8; ++i) {
            const int toff = ((lane & 7) ^ (i & 3)) << 2;
            const float* gp = xb + (i * 8 + c_lo) * 1024 + tbase + toff;
            float* lp = xs + wid * 2048 + i * 256;   // wave-uniform base
            GLL16(gp, lp);
        }
    };

    // producer: gx tile via MFMA, B-frags from LDS
    auto stage1 = [&](int buf, int prefetch_tile) {
        bf16x8 ah[2][2], al[2][2];
        #pragma unroll
        for (int mt = 0; mt < 2; ++mt) {
            const int tS = (mt * 16 + (lane & 15)) ^ ((lane >> 4) << 2);
            #pragma unroll
            for (int kt = 0; kt < 2; ++kt) {
                const int cb = kt * 32 + (lane >> 4) * 8;
                float xf[8];
                #pragma unroll
                for (int j = 0; j < 8; ++j)
                    xf[j] = xs[wid * 2048 + (cb + j) * 32 + tS];
                #pragma unroll
                for (int j = 0; j < 8; ++j) {
                    short hb = f2bf(xf[j]);
                    ah[mt][kt][j] = hb;
                    al[mt][kt][j] = f2bf(xf[j] - bf2f(hb));
                }
            }
        }
        // xs reads drained -> safe to overwrite own xs region
        asm volatile("s_waitcnt lgkmcnt(0)" ::: "memory");
        if (prefetch_tile >= 0) load_xtile(prefetch_tile);

        float* gb = gxs + buf * 12800 + wid * 3200;
        #pragma unroll
        for (int nt = 0; nt < 6; ++nt) {
            bf16x8 bh0 = *(const bf16x8*)(wfH + ((nt)     * 64 + lane) * 8);
            bf16x8 bh1 = *(const bf16x8*)(wfH + ((6 + nt) * 64 + lane) * 8);
            bf16x8 bl0 = *(const bf16x8*)(wfL + ((nt)     * 64 + lane) * 8);
            bf16x8 bl1 = *(const bf16x8*)(wfL + ((6 + nt) * 64 + lane) * 8);
            const float bias = bias6[nt];
            #pragma unroll
            for (int mt = 0; mt < 2; ++mt) {
                f32x4 acc = {bias, bias, bias, bias};
                acc = __builtin_amdgcn_mfma_f32_16x16x32_bf16(ah[mt][0], bh0, acc, 0, 0, 0);
                acc = __builtin_amdgcn_mfma_f32_16x16x32_bf16(ah[mt][1], bh1, acc, 0, 0, 0);
                acc = __builtin_amdgcn_mfma_f32_16x16x32_bf16(ah[mt][0], bl0, acc, 0, 0, 0);
                acc = __builtin_amdgcn_mfma_f32_16x16x32_bf16(ah[mt][1], bl1, acc, 0, 0, 0);
                acc = __builtin_amdgcn_mfma_f32_16x16x32_bf16(al[mt][0], bh0, acc, 0, 0, 0);
                acc = __builtin_amdgcn_mfma_f32_16x16x32_bf16(al[mt][1], bh1, acc, 0, 0, 0);
                // C layout: col = lane&15 (g), row = (lane>>4)*4 + reg (t)
                const int row0 = mt * 16 + ((lane >> 4) << 2);
                const int col  = nt * 16 + (lane & 15);
                #pragma unroll
                for (int j = 0; j < 4; ++j)
                    gb[(row0 + j) * GXS + col] = acc[j];
            }
        }
    };

    // consumer: 32 steps; h broadcast via LDS pair reads, k-split-2
    auto stage2 = [&](int buf) {
        const int bb = wid - 4;
        const float* gb = gxs + buf * 12800 + bb * 3200;
        float* hb = hlds + bb * 32;
        #pragma unroll 4
        for (int s = 0; s < TT; ++s) {
            const float* row = gb + s * GXS;
            float xr = row[h], xz = row[32 + h], xn = row[64 + h];
            hb[h] = hcur;                       // both halves write same value
            asm volatile("s_waitcnt lgkmcnt(0)" ::: "memory");
            f32x2 ar = {0.f, 0.f}, az = {0.f, 0.f}, an = {0.f, 0.f};
            #pragma unroll
            for (int j = 0; j < 8; ++j) {
                f32x2 hp = *(const f32x2*)(hb + k0 + 2 * j);  // uniform/half
                ar.x = fmaf(wr2[j].x, hp.x, ar.x);
                ar.y = fmaf(wr2[j].y, hp.y, ar.y);
                az.x = fmaf(wz2[j].x, hp.x, az.x);
                az.y = fmaf(wz2[j].y, hp.y, az.y);
                an.x = fmaf(wn2[j].x, hp.x, an.x);
                an.y = fmaf(wn2[j].y, hp.y, an.y);
            }
            float ars = ar.x + ar.y;
            float azs = az.x + az.y;
            float ans = an.x + an.y;
            ars += __shfl_xor(ars, 32, 64);
            azs += __shfl_xor(azs, 32, 64);
            ans += __shfl_xor(ans, 32, 64);
            float r  = 1.f / (1.f + __expf(-(xr + ars)));   // xr has b_ih+b_hh
            float z  = 1.f / (1.f + __expf(-(xz + azs)));
            float nx = fmaf(r, ans + bhn, xn);              // bhn inside r*()
            float n  = 1.f - 2.f / (__expf(2.f * nx) + 1.f);
            hcur = n + z * (hcur - n);
        }
    };

    // ================= pipeline =================
    if (wid < 4) load_xtile(0);
    __syncthreads();                    // wfrag ready; xs = tile 0 (vmcnt drained)

    if (wid < 4) stage1(0, 1);          // gxs[0] = tile 0; prefetch tile 1
    __syncthreads();                    // gxs[0] visible; xs = tile 1

    for (int k = 0; k < 32; ++k) {
        if (wid >= 4) {
            stage2(k & 1);
        } else if (k < 31) {
            stage1((k + 1) & 1, (k < 30) ? (k + 2) : -1);
        }
        __syncthreads();
    }

    if (wid >= 4 && lane < 32)
        out[(bid * 4 + (wid - 4)) * 32 + lane] = hcur;
}

extern "C" void kernel_launch(void* const* d_in, const int* in_sizes, int n_in,
                              void* d_out, int out_size, void* d_ws, size_t ws_size,
                              hipStream_t stream) {
    const float* x    = (const float*)d_in[0];
    const float* W_ih = (const float*)d_in[1];
    const float* W_hh = (const float*)d_in[2];
    const float* b_ih = (const float*)d_in[3];
    const float* b_hh = (const float*)d_in[4];
    float* out = (float*)d_out;

    hipFuncSetAttribute((const void*)gru_fused5,
                        hipFuncAttributeMaxDynamicSharedMemorySize, LDS_BYTES);
    gru_fused5<<<256, 512, LDS_BYTES, stream>>>(x, W_ih, W_hh, b_ih, b_hh, out);
}

// Round 8
// 322.639 us; speedup vs baseline: 2.6495x; 1.0398x over previous
//
#include <hip/hip_runtime.h>

// GRU last-hidden: B=1024, C=64, T=1024, H=32, G=96, fp32.
// x:(B,64,1024) W_ih:(96,64) W_hh:(96,32) b_ih,b_hh:(96) out:(B,32)
//
// 256 blocks x 512 threads; block = 4 batches, 8 waves:
//   waves 0-3 = producers: gx tile (32t x 96g) via MFMA bf16 hi/lo 3-product
//   waves 4-7 = consumers (batch = wid-4), gate-split readlane design built
//     ONLY from primitives verified earlier in this problem:
//       lane l: h = l&31. half0 (l<32) computes r-gate matvec (32 w),
//       half1 computes z-gate matvec (32 w); BOTH halves redundantly compute
//       the n-gate matvec (32 w) so no n-combine is needed. 64 weight VGPRs.
//       h broadcast: 32 compile-time v_readlane from hout (lanes 0-31 hold
//       h[0..31]) -> SGPR operand in v_fmac. z shipped to half0 via ONE
//       __shfl_xor(.,32). Gates+update on half0 only; hout IS the broadcast
//       layout (no relayout). Zero LDS and zero DPP/permlane in the h-chain.
//     (R6/R7's DPP-rotation + permlane16/32_swap consumer failed twice on
//      unverifiable semantics — dropped wholesale.)
//
// LDS (156672 B):
//   wfH/wfL: W_ih MFMA B-frags bf16 hi/lo [2kt][6nt][64lane][8]  24576 B
//   xs:      x tiles [4 wave][64 c][32 t], t XOR-swizzled by (c>>3)&3  32768 B
//   gxs:     [2 buf][4 batch][32 t][97] packed [h*3+gate], pad 96->97  99328 B
//            (97 stride: conflict-free producer stores AND consumer reads)

typedef short bf16x8 __attribute__((ext_vector_type(8)));
typedef float f32x4  __attribute__((ext_vector_type(4)));

#define TT 32
#define GXS 97
#define LDS_BYTES 156672

#define GLL16(gp, lp)                                                        \
  __builtin_amdgcn_global_load_lds(                                          \
      (const __attribute__((address_space(1))) void*)(gp),                   \
      (__attribute__((address_space(3))) void*)(lp), 16, 0, 0)

static __device__ __forceinline__ short f2bf(float f) {   // RNE float->bf16
    unsigned u = __float_as_uint(f);
    u += 0x7fffu + ((u >> 16) & 1u);
    return (short)(u >> 16);
}
static __device__ __forceinline__ float bf2f(short s) {
    return __uint_as_float(((unsigned)(unsigned short)s) << 16);
}

__global__ __launch_bounds__(512) void gru_fused8(
    const float* __restrict__ x,
    const float* __restrict__ W_ih,
    const float* __restrict__ W_hh,
    const float* __restrict__ b_ih,
    const float* __restrict__ b_hh,
    float* __restrict__ out)
{
    extern __shared__ char smem[];
    short* wfH = (short*)smem;                    // 768 frags * 8 shorts
    short* wfL = (short*)(smem + 12288);
    float* xs  = (float*)(smem + 24576);          // 4 * 2048 floats
    float* gxs = (float*)(smem + 57344);          // 2*4*32*97 floats

    const int tid  = threadIdx.x;
    const int wid  = tid >> 6;
    const int lane = tid & 63;
    const int bid  = blockIdx.x;

    // ---- one-time: W_ih -> bf16 hi/lo MFMA B-fragments in LDS ----
    for (int f = tid; f < 768; f += 512) {
        int slot = f & 63, ktnt = f >> 6;
        int kt = ktnt / 6, nt = ktnt - kt * 6;
        int g  = nt * 16 + (slot & 15);
        int c0 = kt * 32 + (slot >> 4) * 8;
        const float* wr = W_ih + g * 64 + c0;
        bf16x8 hi, lo;
        #pragma unroll
        for (int j = 0; j < 8; ++j) {
            float v  = wr[j];
            short hb = f2bf(v);
            hi[j] = hb;
            lo[j] = f2bf(v - bf2f(hb));
        }
        *(bf16x8*)(wfH + f * 8) = hi;
        *(bf16x8*)(wfL + f * 8) = lo;
    }

    // ================= producer state =================
    const float* xb = nullptr;
    float bias6[6];
    if (wid < 4) {
        xb = x + (size_t)(bid * 4 + wid) * 64 * 1024;
        #pragma unroll
        for (int nt = 0; nt < 6; ++nt) {
            const int g = nt * 16 + (lane & 15);
            bias6[nt] = b_ih[g] + (nt < 4 ? b_hh[g] : 0.f);  // fold b_hh r/z
        }
    }

    // ================= consumer state (gate-split) =================
    const int h  = lane & 31;
    const int h3 = h * 3;
    float wg_[32], wn_[32];     // wg_: r-row (half0) or z-row (half1); wn_: n-row
    float bhn = 0.f, hout = 0.f;
    if (wid >= 4) {
        const int grow = (lane < 32) ? h : (32 + h);
        #pragma unroll
        for (int j = 0; j < 32; ++j) {
            wg_[j] = W_hh[grow * 32 + j];
            wn_[j] = W_hh[(64 + h) * 32 + j];
        }
        bhn = b_hh[64 + h];
    }

    // async x-tile: lands as xs[c][t ^ (((c>>3)&3)<<2)] (XOR applied to the
    // GLOBAL source t-offset; LDS dest stays linear) -> conflict-free A-reads
    auto load_xtile = [&](int tile) {
        const int tbase = tile * TT;
        const int c_lo  = lane >> 3;
        #pragma unroll
        for (int i = 0; i < 8; ++i) {
            const int toff = ((lane & 7) ^ (i & 3)) << 2;
            const float* gp = xb + (i * 8 + c_lo) * 1024 + tbase + toff;
            float* lp = xs + wid * 2048 + i * 256;   // wave-uniform base
            GLL16(gp, lp);
        }
    };

    // producer: gx tile via MFMA, B-frags from LDS; writes packed [h*3+gate]
    auto stage1 = [&](int buf, int prefetch_tile) {
        bf16x8 ah[2][2], al[2][2];
        #pragma unroll
        for (int mt = 0; mt < 2; ++mt) {
            const int tS = (mt * 16 + (lane & 15)) ^ ((lane >> 4) << 2);
            #pragma unroll
            for (int kt = 0; kt < 2; ++kt) {
                const int cb = kt * 32 + (lane >> 4) * 8;
                float xf[8];
                #pragma unroll
                for (int j = 0; j < 8; ++j)
                    xf[j] = xs[wid * 2048 + (cb + j) * 32 + tS];
                #pragma unroll
                for (int j = 0; j < 8; ++j) {
                    short hb = f2bf(xf[j]);
                    ah[mt][kt][j] = hb;
                    al[mt][kt][j] = f2bf(xf[j] - bf2f(hb));
                }
            }
        }
        // xs reads drained -> safe to overwrite own xs region
        asm volatile("s_waitcnt lgkmcnt(0)" ::: "memory");
        if (prefetch_tile >= 0) load_xtile(prefetch_tile);

        float* gb = gxs + buf * 12416 + wid * 3104;
        #pragma unroll
        for (int nt = 0; nt < 6; ++nt) {
            bf16x8 bh0 = *(const bf16x8*)(wfH + ((nt)     * 64 + lane) * 8);
            bf16x8 bh1 = *(const bf16x8*)(wfH + ((6 + nt) * 64 + lane) * 8);
            bf16x8 bl0 = *(const bf16x8*)(wfL + ((nt)     * 64 + lane) * 8);
            bf16x8 bl1 = *(const bf16x8*)(wfL + ((6 + nt) * 64 + lane) * 8);
            const float bias = bias6[nt];
            const int g    = nt * 16 + (lane & 15);
            const int off  = (g & 31) * 3 + (g >> 5);      // packed column
            #pragma unroll
            for (int mt = 0; mt < 2; ++mt) {
                f32x4 acc = {bias, bias, bias, bias};
                acc = __builtin_amdgcn_mfma_f32_16x16x32_bf16(ah[mt][0], bh0, acc, 0, 0, 0);
                acc = __builtin_amdgcn_mfma_f32_16x16x32_bf16(ah[mt][1], bh1, acc, 0, 0, 0);
                acc = __builtin_amdgcn_mfma_f32_16x16x32_bf16(ah[mt][0], bl0, acc, 0, 0, 0);
                acc = __builtin_amdgcn_mfma_f32_16x16x32_bf16(ah[mt][1], bl1, acc, 0, 0, 0);
                acc = __builtin_amdgcn_mfma_f32_16x16x32_bf16(al[mt][0], bh0, acc, 0, 0, 0);
                acc = __builtin_amdgcn_mfma_f32_16x16x32_bf16(al[mt][1], bh1, acc, 0, 0, 0);
                // C layout: col = lane&15 (g), row = (lane>>4)*4 + reg (t)
                const int row0 = mt * 16 + ((lane >> 4) << 2);
                #pragma unroll
                for (int j = 0; j < 4; ++j)
                    gb[(row0 + j) * GXS + off] = acc[j];
            }
        }
    };

    // consumer: 32 steps; h broadcast via 32 compile-time readlanes (SGPR),
    // z matvec shipped half1->half0 via one shfl_xor. No LDS in the chain.
    auto stage2 = [&](int buf) {
        const float* gb = gxs + buf * 12416 + (wid - 4) * 3104;
        #pragma unroll 2
        for (int s = 0; s < TT; ++s) {
            const float* row = gb + s * GXS + h3;
            float xr = row[0], xz = row[1], xn = row[2];
            float a0 = 0.f, a1 = 0.f, n0 = 0.f, n1 = 0.f;
            const int hb = __float_as_int(hout);
            #pragma unroll
            for (int j = 0; j < 32; j += 2) {
                float s0 = __int_as_float(__builtin_amdgcn_readlane(hb, j));
                float s1 = __int_as_float(__builtin_amdgcn_readlane(hb, j + 1));
                a0 = fmaf(wg_[j],     s0, a0);
                a1 = fmaf(wg_[j + 1], s1, a1);
                n0 = fmaf(wn_[j],     s0, n0);
                n1 = fmaf(wn_[j + 1], s1, n1);
            }
            float accA = a0 + a1;                    // r (half0) / z (half1)
            float accN = n0 + n1;                    // n (both halves)
            float accZ = __shfl_xor(accA, 32, 64);   // half0 receives z matvec
            if (lane < 32) {
                float r  = __builtin_amdgcn_rcpf(1.f + __expf(-(xr + accA)));
                float z  = __builtin_amdgcn_rcpf(1.f + __expf(-(xz + accZ)));
                float nx = fmaf(r, accN + bhn, xn);
                float n  = 1.f - 2.f * __builtin_amdgcn_rcpf(__expf(2.f * nx) + 1.f);
                hout = n + z * (hout - n);           // lanes 0-31 hold h[0..31]
            }
        }
    };

    // ================= pipeline =================
    if (wid < 4) load_xtile(0);
    __syncthreads();                    // wfrag ready; xs = tile 0 (vmcnt drained)

    if (wid < 4) stage1(0, 1);          // gxs[0] = tile 0; prefetch tile 1
    __syncthreads();                    // gxs[0] visible; xs = tile 1

    for (int k = 0; k < 32; ++k) {
        if (wid >= 4) {
            stage2(k & 1);
        } else if (k < 31) {
            stage1((k + 1) & 1, (k < 30) ? (k + 2) : -1);
        }
        __syncthreads();
    }

    if (wid >= 4 && lane < 32)
        out[(bid * 4 + (wid - 4)) * 32 + lane] = hout;
}

extern "C" void kernel_launch(void* const* d_in, const int* in_sizes, int n_in,
                              void* d_out, int out_size, void* d_ws, size_t ws_size,
                              hipStream_t stream) {
    const float* x    = (const float*)d_in[0];
    const float* W_ih = (const float*)d_in[1];
    const float* W_hh = (const float*)d_in[2];
    const float* b_ih = (const float*)d_in[3];
    const float* b_hh = (const float*)d_in[4];
    float* out = (float*)d_out;

    hipFuncSetAttribute((const void*)gru_fused8,
                        hipFuncAttributeMaxDynamicSharedMemorySize, LDS_BYTES);
    gru_fused8<<<256, 512, LDS_BYTES, stream>>>(x, W_ih, W_hh, b_ih, b_hh, out);
}